// Round 17
// baseline (843.884 us; speedup 1.0000x reference)
//
#include <hip/hip_runtime.h>
#include <hip/hip_bf16.h>
#include <cstdint>
#include <cstddef>

#define ALPHA 0.1f
#define K_ITERS 10
#define NPART 8

typedef __attribute__((ext_vector_type(8))) short bf16x8;
typedef __attribute__((ext_vector_type(4))) float f32x4;
typedef __attribute__((ext_vector_type(4))) unsigned int u32x4;

#define U15INV (1.0f / 32767.0f)

__device__ __forceinline__ unsigned short f2bf(float f) {
    unsigned int u = __float_as_uint(f);
    u += 0x7fffu + ((u >> 16) & 1u);          // RNE
    return (unsigned short)(u >> 16);
}
__device__ __forceinline__ float bflo(unsigned int u) {
    return __uint_as_float(u << 16);
}
__device__ __forceinline__ float bfhi(unsigned int u) {
    return __uint_as_float(u & 0xffff0000u);
}
__device__ __forceinline__ unsigned int pack2(float a, float b) {
    return (unsigned int)f2bf(a) | ((unsigned int)f2bf(b) << 16);
}
__device__ __forceinline__ unsigned int u15q(float w) {   // w in [0,1]
    return (unsigned int)(w * 32767.0f + 0.5f);
}
__device__ __forceinline__ int xcd_id() {
    unsigned int x;
    asm volatile("s_getreg_b32 %0, hwreg(20, 0, 32)" : "=s"(x));   // HW_REG_XCC_ID (gfx950)
    return (int)(x & (NPART - 1));
}

// ---------------- helper kernels ----------------

// setup: zero cnt partitions + flag (cs pads are zeroed in scan3 now)
__global__ __launch_bounds__(256) void setup_k(int* cntp, int* flag, int ncnt) {
    int i = blockIdx.x * 256 + threadIdx.x;
    if (i == 0) *flag = 0;
    if (i < ncnt) cntp[i] = 0;
}

// Detect whether edge_index buffer is int64 (values in [0,N) when read as ll) or int32.
__global__ void detect_idx_k(const void* ei, int* flag, int E_, int N_) {
    int tid = threadIdx.x;
    const long long* p = (const long long*)ei;
    int bad = 0;
    int lim = (E_ < 4096) ? E_ : 4096;
    for (int i = tid; i < lim; i += 256) {
        long long v = p[i];
        if (v < 0 || v >= (long long)N_) bad = 1;
    }
    if (bad) atomicOr(flag, 1);   // 1 => buffer is int32
}

// fused weight prep:
// idx < F*D:  W1bT[n][k] = bf16( W1[k][n] * sigmoid_mask(xw[k]) )
// else:       W2bT[n][k] = bf16( W2[k][n] )
__global__ __launch_bounds__(256) void wprep_k(const float* W1, const float* xw, unsigned short* W1bT,
                                               const float* W2, unsigned short* W2bT,
                                               int F_, int D_, int C_) {
    int i = blockIdx.x * 256 + threadIdx.x;
    int n1 = F_ * D_;
    if (i < n1) {
        int k = i / D_, n = i % D_;
        float t = xw[k];
        float s = (fabsf(t) > 0.0f) ? 1.0f / (1.0f + expf(-t)) : 0.0f;
        W1bT[(size_t)n * F_ + k] = f2bf(W1[i] * s);
    } else if (i < n1 + D_ * C_) {
        int j = i - n1;
        int k = j / C_, n = j % C_;
        W2bT[(size_t)n * D_ + k] = f2bf(W2[j]);
    }
}

// ---------------- MERGED: fused MLP (blocks [0,gx)) + edge prep (blocks [gx,..)) ----------------
// 48KB LDS (staging 48KB; h consumed in two 32KB half-passes) -> 3 blocks/CU.
__global__ __launch_bounds__(512) void mlp_prep_k(
        // gemm args
        const float* __restrict__ A, const unsigned short* __restrict__ BT,
        const float* __restrict__ b1, const unsigned short* __restrict__ W2bT,
        const float* __restrict__ b2, unsigned short* __restrict__ z0out,
        int M, int K, int Nn, int Cn, int gx,
        // prep args
        const void* __restrict__ ei, const float* __restrict__ ew,
        unsigned long long* __restrict__ epack, int* __restrict__ cntp,
        const int* __restrict__ flag, int E_, int N_) {
    __shared__ __align__(16) unsigned short SMEM[24576];   // 48KB union

    if (blockIdx.x >= gx) {
        // ---------------- prep path: 512 edges per block ----------------
        int e = (blockIdx.x - gx) * 512 + threadIdx.x;
        if (e >= E_) return;
        int is32 = *flag;
        unsigned long long r, c;
        if (is32) {
            const int* p = (const int*)ei;
            r = (unsigned long long)(unsigned int)p[e];
            c = (unsigned long long)(unsigned int)p[(size_t)E_ + e];
        } else {
            const long long* p = (const long long*)ei;
            r = (unsigned long long)p[e];
            c = (unsigned long long)p[(size_t)E_ + e];
        }
        float t = ew[e];
        float wv = (fabsf(t) > 0.0f) ? 1.0f / (1.0f + expf(-t)) : 0.0f;
        unsigned long long part = (unsigned long long)xcd_id();
        unsigned long long rk = (unsigned long long)(unsigned int)
            __hip_atomic_fetch_add(&cntp[(size_t)part * N_ + (int)c], 1,
                                   __ATOMIC_RELAXED, __HIP_MEMORY_SCOPE_WORKGROUP);
        epack[e] = r | (c << 17) | ((unsigned long long)u15q(wv) << 34)
                     | (part << 49) | (rk << 52);
        return;
    }

    // ---------------- gemm path: fused z0 = relu(x@W1p+b1)@W2+b2 ----------------
    const int BK = 32;
    typedef unsigned short (*AslT)[4][128][8];   // 16KB @0
    typedef unsigned short (*BslT)[4][256][8];   // 32KB @8192
    AslT Asl = (AslT)SMEM;
    BslT Bsl = (BslT)(SMEM + 8192);

    int tid = threadIdx.x;
    int row0 = blockIdx.x * 128;
    int wid = tid >> 6, lane = tid & 63;
    int wm = wid & 1, wn = wid >> 1;           // 2x4 wave grid, wave tile 64x64
    int lrow = lane & 15, kg = lane >> 4;

    f32x4 acc[4][4];
    #pragma unroll
    for (int i = 0; i < 4; ++i)
        #pragma unroll
        for (int j = 0; j < 4; ++j) acc[i][j] = (f32x4){0.f, 0.f, 0.f, 0.f};

    int ar = tid >> 2, akg = tid & 3;          // A: row, kgroup (8 floats)
    int agrow = row0 + ar;
    bool avalid = agrow < M;
    int bn_ = tid >> 1, bkh = (tid & 1) * 16;  // B: col, k-half (16 bf16)

    float fa[8];
    bf16x8 bv0, bv1;

    auto loadTile = [&](int k0) {
        if (avalid) {
            const f32x4* p = (const f32x4*)&A[(size_t)agrow * K + k0 + akg * 8];
            *(f32x4*)&fa[0] = p[0];
            *(f32x4*)&fa[4] = p[1];
        }
        const bf16x8* p = (const bf16x8*)&BT[(size_t)bn_ * K + k0 + bkh];
        bv0 = p[0]; bv1 = p[1];
    };
    auto stageTile = [&](int buf) {
        unsigned short av[8];
        #pragma unroll
        for (int q = 0; q < 8; ++q) av[q] = avalid ? f2bf(fa[q]) : (unsigned short)0;
        *(bf16x8*)&Asl[buf][akg][ar][0] = *(bf16x8*)&av[0];
        *(bf16x8*)&Bsl[buf][(bkh >> 3) + 0][bn_][0] = bv0;
        *(bf16x8*)&Bsl[buf][(bkh >> 3) + 1][bn_][0] = bv1;
    };

    int nsteps = K / BK;
    loadTile(0);
    stageTile(0);
    __syncthreads();

    int cur = 0;
    for (int step = 0; step < nsteps; ++step) {
        bool more = (step + 1) < nsteps;
        if (more) loadTile((step + 1) * BK);

        bf16x8 af[4], bfr[4];
        #pragma unroll
        for (int i = 0; i < 4; ++i)
            af[i] = *(bf16x8*)&Asl[cur][kg][wm * 64 + i * 16 + lrow][0];
        #pragma unroll
        for (int j = 0; j < 4; ++j)
            bfr[j] = *(bf16x8*)&Bsl[cur][kg][wn * 64 + j * 16 + lrow][0];
        #pragma unroll
        for (int i = 0; i < 4; ++i)
            #pragma unroll
            for (int j = 0; j < 4; ++j)
                acc[i][j] = __builtin_amdgcn_mfma_f32_16x16x32_bf16(af[i], bfr[j], acc[i][j], 0, 0, 0);

        if (more) stageTile(cur ^ 1);
        __syncthreads();
        cur ^= 1;
    }

    // ---- phases 2/3 in two k2-halves (32KB H region at SMEM[0..16384)) ----
    f32x4 acc2[4];
    #pragma unroll
    for (int i = 0; i < 4; ++i) acc2[i] = (f32x4){0.f, 0.f, 0.f, 0.f};
    int col2 = wn * 16 + lrow;

    #pragma unroll
    for (int p = 0; p < 2; ++p) {
        // phase 2: waves owning k2 in [p*128,(p+1)*128) write h half (bias+relu, bf16)
        if ((wn >> 1) == p) {
            #pragma unroll
            for (int i = 0; i < 4; ++i) {
                #pragma unroll
                for (int j = 0; j < 4; ++j) {
                    int k2 = wn * 64 + j * 16 + lrow;        // global k2
                    int k2l = k2 - p * 128;                   // local in half
                    float bv = b1[k2];
                    int base = ((k2l >> 5) * 4 + ((k2l >> 3) & 3)) * 1024 + (k2l & 7);
                    #pragma unroll
                    for (int r = 0; r < 4; ++r) {
                        int row = wm * 64 + i * 16 + kg * 4 + r;
                        float v = fmaxf(acc[i][j][r] + bv, 0.0f);
                        SMEM[base + row * 8] = f2bf(v);
                    }
                }
            }
        }
        __syncthreads();
        // phase 3: all 8 waves accumulate over this half's 4 chunks of 32
        #pragma unroll
        for (int ch = 0; ch < 4; ++ch) {
            bf16x8 bfr2 = *(const bf16x8*)&W2bT[(size_t)col2 * Nn + p * 128 + ch * 32 + kg * 8];
            bf16x8 af2[4];
            #pragma unroll
            for (int i = 0; i < 4; ++i)
                af2[i] = *(bf16x8*)&SMEM[(ch * 4 + kg) * 1024 + (wm * 64 + i * 16 + lrow) * 8];
            #pragma unroll
            for (int i = 0; i < 4; ++i)
                acc2[i] = __builtin_amdgcn_mfma_f32_16x16x32_bf16(af2[i], bfr2, acc2[i], 0, 0, 0);
        }
        __syncthreads();
    }

    float bv2 = b2[col2];
    #pragma unroll
    for (int i = 0; i < 4; ++i) {
        #pragma unroll
        for (int r = 0; r < 4; ++r) {
            int grow = row0 + wm * 64 + i * 16 + kg * 4 + r;
            if (grow < M)
                z0out[(size_t)grow * Cn + col2] = f2bf(acc2[i][r] + bv2);
        }
    }
}

// per-node: prefix over NPART partition counts -> pofs; true total -> cntT;
// padded total -> cnt8; block-reduced sum of cnt8 -> bsum (merged scan1)
__global__ __launch_bounds__(256) void combine_k(const int* cntp, int* pofs, int* cntT,
                                                 int* cnt8, int* bsum, int N_) {
    __shared__ int sm[256];
    int t = threadIdx.x;
    int i = blockIdx.x * 256 + t;
    int c8 = 0;
    if (i < N_) {
        int s = 0;
        #pragma unroll
        for (int p = 0; p < NPART; ++p) {
            size_t idx = (size_t)p * N_ + i;
            int v = cntp[idx];
            pofs[idx] = s;
            s += v;
        }
        cntT[i] = s;
        c8 = (s + 7) & ~7;
        cnt8[i] = c8;
    }
    sm[t] = c8;
    __syncthreads();
    for (int off = 128; off; off >>= 1) {
        if (t < off) sm[t] += sm[t + off];
        __syncthreads();
    }
    if (t == 0) bsum[blockIdx.x] = sm[0];
}

__global__ __launch_bounds__(1024) void scan2_k(const int* bsum, int* boff, int nb) {
    __shared__ int sm[1024];
    int t = threadIdx.x;
    int v = (t < nb) ? bsum[t] : 0;
    sm[t] = v;
    __syncthreads();
    for (int off = 1; off < 1024; off <<= 1) {
        int x = (t >= off) ? sm[t - off] : 0;
        __syncthreads();
        sm[t] += x;
        __syncthreads();
    }
    if (t < nb) boff[t] = sm[t] - v;   // exclusive
}

// scan3: rowstart + zero the pad entries of cs (positions [cntT, cnt8) per row)
__global__ __launch_bounds__(256) void scan3_k(const int* cnt8, const int* cntT, const int* boff,
                                               int* rowstart, unsigned int* cs, int N_) {
    __shared__ int sm[256];
    int t = threadIdx.x, i = blockIdx.x * 256 + t;
    int v = (i < N_) ? cnt8[i] : 0;
    sm[t] = v;
    __syncthreads();
    for (int off = 1; off < 256; off <<= 1) {
        int x = (t >= off) ? sm[t - off] : 0;
        __syncthreads();
        sm[t] += x;
        __syncthreads();
    }
    if (i < N_) {
        int base = boff[blockIdx.x] + sm[t] - v;
        rowstart[i] = base;
        int st = cntT[i];
        for (int j = st; j < v; ++j) cs[base + j] = 0;   // pads: src=0,w=0
    }
    if (i == N_ - 1) rowstart[N_] = boff[blockIdx.x] + sm[t];
}

// atomic-free CSR fill: pos = rowstart[c] + pofs[part][c] + rank
// csr entry: src:17 | unorm15(w) << 17
__global__ __launch_bounds__(256) void fill_csr_k(const unsigned long long* epack, const int* pofs,
                                                  const int* rowstart, unsigned int* cs,
                                                  int E_, int N_) {
    int e = blockIdx.x * 256 + threadIdx.x;
    if (e >= E_) return;
    unsigned long long v = epack[e];
    unsigned int r   = (unsigned int)(v & 0x1ffffu);
    int          c   = (int)((v >> 17) & 0x1ffffu);
    unsigned int w15 = (unsigned int)((v >> 34) & 0x7fffu);
    int         part = (int)((v >> 49) & 7u);
    int           rk = (int)(v >> 52);
    int pos = rowstart[c] + pofs[(size_t)part * N_ + c] + rk;
    cs[pos] = r | (w15 << 17);
}

// 32-lane group per node: deg = 1 + sum(w over row, pads are 0); dinv = rsqrt
__global__ __launch_bounds__(256) void deg_dinv_k(const unsigned int* __restrict__ cs,
                                                  const int* __restrict__ rowstart,
                                                  float* __restrict__ dinv, int N_) {
    int node = blockIdx.x * 8 + (threadIdx.x >> 5);
    int l = threadIdx.x & 31;
    if (node >= N_) return;
    int s = rowstart[node], e = rowstart[node + 1];
    float sum = 0.0f;
    for (int j = s + l; j < e; j += 32) sum += (float)(cs[j] >> 17) * U15INV;
    #pragma unroll
    for (int off = 16; off; off >>= 1) sum += __shfl_xor(sum, off, 64);
    float d = sum + 1.0f;   // self-loop
    if (l == 0) dinv[node] = (d > 0.0f) ? rsqrtf(fmaxf(d, 1e-12f)) : 0.0f;
}

// ---------------- propagation: 8 lanes per node, 8 nodes per wave ----------------
// MODE 0: middle iteration. MODE 1: FIRST iteration — cs holds raw w; compute
// nm = dinv[src]*w*dinv[dst] on the fly, use it, write back quantized (lane 0).
// MODE 2: LAST iteration — fused log_softmax, fp32 out.
template<int MODE>
__global__ __launch_bounds__(256) void prop8_k(const unsigned short* __restrict__ z,
                                               const unsigned short* __restrict__ z0,
                                               const int* __restrict__ rowstart,
                                               unsigned int* __restrict__ cs,
                                               const float* __restrict__ dinv,
                                               unsigned short* __restrict__ znew,
                                               float* __restrict__ out, int N_) {
    int node = blockIdx.x * 32 + (threadIdx.x >> 3);
    int l = threadIdx.x & 7;
    if (node >= N_) return;
    int s = rowstart[node], e = rowstart[node + 1];   // multiples of 8
    float d = dinv[node];
    size_t ro = (size_t)node * 64 + l * 8;
    u32x4 zs = *(const u32x4*)&z[ro];
    float dd = d * d;
    float a[8];
    a[0] = dd * bflo(zs.x); a[1] = dd * bfhi(zs.x);
    a[2] = dd * bflo(zs.y); a[3] = dd * bfhi(zs.y);
    a[4] = dd * bflo(zs.z); a[5] = dd * bfhi(zs.z);
    a[6] = dd * bflo(zs.w); a[7] = dd * bfhi(zs.w);

    for (int j = s; j < e; j += 8) {
        u32x4 p0 = __builtin_nontemporal_load((const u32x4*)&cs[j]);
        u32x4 p1 = __builtin_nontemporal_load((const u32x4*)&cs[j + 4]);
        unsigned int pe[8] = { p0.x, p0.y, p0.z, p0.w, p1.x, p1.y, p1.z, p1.w };
        u32x4 g[8];
        #pragma unroll
        for (int q = 0; q < 8; ++q)
            g[q] = *(const u32x4*)&z[(size_t)(pe[q] & 0x1ffffu) * 64 + l * 8];
        if (MODE == 1) {
            float dv[8];
            #pragma unroll
            for (int q = 0; q < 8; ++q) dv[q] = dinv[pe[q] & 0x1ffffu];
            unsigned int ow[8];
            #pragma unroll
            for (int q = 0; q < 8; ++q) {
                float wraw = (float)(pe[q] >> 17) * U15INV;
                float nm = dv[q] * wraw * d;
                ow[q] = (pe[q] & 0x1ffffu) | (u15q(nm) << 17);
                a[0] += nm * bflo(g[q].x); a[1] += nm * bfhi(g[q].x);
                a[2] += nm * bflo(g[q].y); a[3] += nm * bfhi(g[q].y);
                a[4] += nm * bflo(g[q].z); a[5] += nm * bfhi(g[q].z);
                a[6] += nm * bflo(g[q].w); a[7] += nm * bfhi(g[q].w);
            }
            if (l == 0) {
                u32x4 o0, o1;
                o0.x = ow[0]; o0.y = ow[1]; o0.z = ow[2]; o0.w = ow[3];
                o1.x = ow[4]; o1.y = ow[5]; o1.z = ow[6]; o1.w = ow[7];
                *(u32x4*)&cs[j] = o0;
                *(u32x4*)&cs[j + 4] = o1;
            }
        } else {
            #pragma unroll
            for (int q = 0; q < 8; ++q) {
                float w = (float)(pe[q] >> 17) * U15INV;
                a[0] += w * bflo(g[q].x); a[1] += w * bfhi(g[q].x);
                a[2] += w * bflo(g[q].y); a[3] += w * bfhi(g[q].y);
                a[4] += w * bflo(g[q].z); a[5] += w * bfhi(g[q].z);
                a[6] += w * bflo(g[q].w); a[7] += w * bfhi(g[q].w);
            }
        }
    }

    u32x4 z0v = __builtin_nontemporal_load((const u32x4*)&z0[ro]);
    float v[8];
    float z0f[8] = { bflo(z0v.x), bfhi(z0v.x), bflo(z0v.y), bfhi(z0v.y),
                     bflo(z0v.z), bfhi(z0v.z), bflo(z0v.w), bfhi(z0v.w) };
    #pragma unroll
    for (int q = 0; q < 8; ++q) v[q] = (1.0f - ALPHA) * a[q] + ALPHA * z0f[q];

    if (MODE != 2) {
        u32x4 o;
        o.x = pack2(v[0], v[1]); o.y = pack2(v[2], v[3]);
        o.z = pack2(v[4], v[5]); o.w = pack2(v[6], v[7]);
        *(u32x4*)&znew[ro] = o;      // normal store: let z dwell in L2
    } else {
        float m = v[0];
        #pragma unroll
        for (int q = 1; q < 8; ++q) m = fmaxf(m, v[q]);
        #pragma unroll
        for (int off = 1; off < 8; off <<= 1) m = fmaxf(m, __shfl_xor(m, off, 64));
        float sum = 0.0f;
        #pragma unroll
        for (int q = 0; q < 8; ++q) sum += expf(v[q] - m);
        #pragma unroll
        for (int off = 1; off < 8; off <<= 1) sum += __shfl_xor(sum, off, 64);
        float lg = logf(sum);
        float4 o0 = make_float4(v[0] - m - lg, v[1] - m - lg, v[2] - m - lg, v[3] - m - lg);
        float4 o1 = make_float4(v[4] - m - lg, v[5] - m - lg, v[6] - m - lg, v[7] - m - lg);
        *(float4*)&out[ro] = o0;
        *(float4*)&out[ro + 4] = o1;
    }
}

// ---------------- launcher ----------------

extern "C" void kernel_launch(void* const* d_in, const int* in_sizes, int n_in,
                              void* d_out, int out_size, void* d_ws, size_t ws_size,
                              hipStream_t stream) {
    const float* x   = (const float*)d_in[0];
    const void*  ei  = d_in[1];
    const float* ew  = (const float*)d_in[2];
    const float* xw  = (const float*)d_in[3];
    const float* W1  = (const float*)d_in[4];
    const float* b1  = (const float*)d_in[5];
    const float* W2  = (const float*)d_in[6];
    const float* b2  = (const float*)d_in[7];

    const int F_ = in_sizes[3];          // 512
    const int N_ = in_sizes[0] / F_;     // 100000
    const int E_ = in_sizes[2];          // 3200000
    const int D_ = in_sizes[5];          // 256
    const int C_ = in_sizes[7];          // 64

    const int E8 = E_ + 7 * N_;          // upper bound on padded edge count

    char* base = (char*)d_ws;
    size_t off = 0;
    auto take = [&](size_t bytes) -> void* {
        void* p = base + off;
        off += (bytes + 255) & ~(size_t)255;
        return p;
    };
    unsigned long long* epack = (unsigned long long*)take((size_t)E_ * 8);
    unsigned int* cs = (unsigned int*)take((size_t)E8 * 4);
    int*   cntp     = (int*)  take((size_t)NPART * N_ * 4);
    int*   pofs     = (int*)  take((size_t)NPART * N_ * 4);
    int*   cntT     = (int*)  take((size_t)N_ * 4);
    int*   cnt8     = (int*)  take((size_t)N_ * 4);
    float* dinv     = (float*)take((size_t)N_ * 4);
    int*   rowstart = (int*)  take((size_t)(N_ + 1) * 4);
    int*   flag     = (int*)  take(256);
    int*   bsum     = (int*)  take(4096 * 4);
    int*   boff     = (int*)  take(4096 * 4);
    unsigned short* W1bT = (unsigned short*)take((size_t)F_ * D_ * 2);
    unsigned short* W2bT = (unsigned short*)take((size_t)D_ * C_ * 2);
    unsigned short* z0b  = (unsigned short*)take((size_t)N_ * C_ * 2);
    unsigned short* za   = (unsigned short*)take((size_t)N_ * C_ * 2);
    unsigned short* zb   = (unsigned short*)take((size_t)N_ * C_ * 2);

    (void)ws_size; (void)n_in; (void)out_size;

    int nblk = (N_ + 255) / 256;
    int eblk = (E_ + 255) / 256;
    int ncnt = NPART * N_;

    setup_k<<<(ncnt + 255) / 256, 256, 0, stream>>>(cntp, flag, ncnt);
    detect_idx_k<<<1, 256, 0, stream>>>(ei, flag, E_, N_);
    wprep_k<<<(F_ * D_ + D_ * C_ + 255) / 256, 256, 0, stream>>>(W1, xw, W1bT, W2, W2bT, F_, D_, C_);

    // MERGED: fused MLP (first gx blocks) + edge prep (remaining blocks)
    int gx = (N_ + 127) / 128;
    int eblk512 = (E_ + 511) / 512;
    mlp_prep_k<<<gx + eblk512, 512, 0, stream>>>(
        x, W1bT, b1, W2bT, b2, z0b, N_, F_, D_, C_, gx,
        ei, ew, epack, cntp, flag, E_, N_);

    combine_k<<<nblk, 256, 0, stream>>>(cntp, pofs, cntT, cnt8, bsum, N_);
    scan2_k<<<1, 1024, 0, stream>>>(bsum, boff, nblk);
    scan3_k<<<nblk, 256, 0, stream>>>(cnt8, cntT, boff, rowstart, cs, N_);
    fill_csr_k<<<eblk, 256, 0, stream>>>(epack, pofs, rowstart, cs, E_, N_);
    int gblk8 = (N_ + 7) / 8;
    deg_dinv_k<<<gblk8, 256, 0, stream>>>(cs, rowstart, dinv, N_);

    int pblk = (N_ + 31) / 32;
    unsigned short* bufs[2] = { za, zb };
    // it 0: norm fused (cs raw w -> normalized in place), reads z0b
    prop8_k<1><<<pblk, 256, 0, stream>>>(z0b, z0b, rowstart, cs, dinv, za, nullptr, N_);
    const unsigned short* cur = za;
    for (int it = 1; it < K_ITERS - 1; ++it) {
        unsigned short* dst = bufs[it & 1];
        prop8_k<0><<<pblk, 256, 0, stream>>>(cur, z0b, rowstart, cs, dinv, dst, nullptr, N_);
        cur = dst;
    }
    prop8_k<2><<<pblk, 256, 0, stream>>>(cur, z0b, rowstart, cs, dinv, nullptr, (float*)d_out, N_);
}

// Round 18
// 838.800 us; speedup vs baseline: 1.0061x; 1.0061x over previous
//
#include <hip/hip_runtime.h>
#include <hip/hip_bf16.h>
#include <cstdint>
#include <cstddef>

#define ALPHA 0.1f
#define K_ITERS 10
#define NPART 8

typedef __attribute__((ext_vector_type(8))) short bf16x8;
typedef __attribute__((ext_vector_type(4))) float f32x4;
typedef __attribute__((ext_vector_type(4))) unsigned int u32x4;

#define U15INV (1.0f / 32767.0f)

__device__ __forceinline__ unsigned short f2bf(float f) {
    unsigned int u = __float_as_uint(f);
    u += 0x7fffu + ((u >> 16) & 1u);          // RNE
    return (unsigned short)(u >> 16);
}
__device__ __forceinline__ float bflo(unsigned int u) {
    return __uint_as_float(u << 16);
}
__device__ __forceinline__ float bfhi(unsigned int u) {
    return __uint_as_float(u & 0xffff0000u);
}
__device__ __forceinline__ unsigned int pack2(float a, float b) {
    return (unsigned int)f2bf(a) | ((unsigned int)f2bf(b) << 16);
}
__device__ __forceinline__ unsigned int u15q(float w) {   // w in [0,1]
    return (unsigned int)(w * 32767.0f + 0.5f);
}
__device__ __forceinline__ int xcd_id() {
    unsigned int x;
    asm volatile("s_getreg_b32 %0, hwreg(20, 0, 32)" : "=s"(x));   // HW_REG_XCC_ID (gfx950)
    return (int)(x & (NPART - 1));
}

// ---------------- helper kernels ----------------

// setup: zero cnt partitions + flag (cs pads are zeroed in scan3)
__global__ __launch_bounds__(256) void setup_k(int* cntp, int* flag, int ncnt) {
    int i = blockIdx.x * 256 + threadIdx.x;
    if (i == 0) *flag = 0;
    if (i < ncnt) cntp[i] = 0;
}

// Detect whether edge_index buffer is int64 (values in [0,N) when read as ll) or int32.
__global__ void detect_idx_k(const void* ei, int* flag, int E_, int N_) {
    int tid = threadIdx.x;
    const long long* p = (const long long*)ei;
    int bad = 0;
    int lim = (E_ < 4096) ? E_ : 4096;
    for (int i = tid; i < lim; i += 256) {
        long long v = p[i];
        if (v < 0 || v >= (long long)N_) bad = 1;
    }
    if (bad) atomicOr(flag, 1);   // 1 => buffer is int32
}

// fused weight prep:
// idx < F*D:  W1bT[n][k] = bf16( W1[k][n] * sigmoid_mask(xw[k]) )
// else:       W2bT[n][k] = bf16( W2[k][n] )
__global__ __launch_bounds__(256) void wprep_k(const float* W1, const float* xw, unsigned short* W1bT,
                                               const float* W2, unsigned short* W2bT,
                                               int F_, int D_, int C_) {
    int i = blockIdx.x * 256 + threadIdx.x;
    int n1 = F_ * D_;
    if (i < n1) {
        int k = i / D_, n = i % D_;
        float t = xw[k];
        float s = (fabsf(t) > 0.0f) ? 1.0f / (1.0f + expf(-t)) : 0.0f;
        W1bT[(size_t)n * F_ + k] = f2bf(W1[i] * s);
    } else if (i < n1 + D_ * C_) {
        int j = i - n1;
        int k = j / C_, n = j % C_;
        W2bT[(size_t)n * D_ + k] = f2bf(W2[j]);
    }
}

// ---------------- MERGED: fused MLP (blocks [0,gx)) + edge prep (blocks [gx,..)) ----------------
// 64KB LDS union; single-pass phase2/3 (R16 structure — measured fastest).
__global__ __launch_bounds__(512) void mlp_prep_k(
        // gemm args
        const float* __restrict__ A, const unsigned short* __restrict__ BT,
        const float* __restrict__ b1, const unsigned short* __restrict__ W2bT,
        const float* __restrict__ b2, unsigned short* __restrict__ z0out,
        int M, int K, int Nn, int Cn, int gx,
        // prep args
        const void* __restrict__ ei, const float* __restrict__ ew,
        unsigned long long* __restrict__ epack, int* __restrict__ cntp,
        const int* __restrict__ flag, int E_, int N_) {
    __shared__ __align__(16) unsigned short SMEM[32768];   // 64KB union (gemm path only)

    if (blockIdx.x >= gx) {
        // ---------------- prep path: 512 edges per block ----------------
        int e = (blockIdx.x - gx) * 512 + threadIdx.x;
        if (e >= E_) return;
        int is32 = *flag;
        unsigned long long r, c;
        if (is32) {
            const int* p = (const int*)ei;
            r = (unsigned long long)(unsigned int)p[e];
            c = (unsigned long long)(unsigned int)p[(size_t)E_ + e];
        } else {
            const long long* p = (const long long*)ei;
            r = (unsigned long long)p[e];
            c = (unsigned long long)p[(size_t)E_ + e];
        }
        float t = ew[e];
        float wv = (fabsf(t) > 0.0f) ? 1.0f / (1.0f + expf(-t)) : 0.0f;
        unsigned long long part = (unsigned long long)xcd_id();
        unsigned long long rk = (unsigned long long)(unsigned int)
            __hip_atomic_fetch_add(&cntp[(size_t)part * N_ + (int)c], 1,
                                   __ATOMIC_RELAXED, __HIP_MEMORY_SCOPE_WORKGROUP);
        epack[e] = r | (c << 17) | ((unsigned long long)u15q(wv) << 34)
                     | (part << 49) | (rk << 52);
        return;
    }

    // ---------------- gemm path: fused z0 = relu(x@W1p+b1)@W2+b2 ----------------
    const int BK = 32;
    typedef unsigned short (*AslT)[4][128][8];
    typedef unsigned short (*BslT)[4][256][8];
    AslT Asl = (AslT)SMEM;
    BslT Bsl = (BslT)(SMEM + 8192);

    int tid = threadIdx.x;
    int row0 = blockIdx.x * 128;
    int wid = tid >> 6, lane = tid & 63;
    int wm = wid & 1, wn = wid >> 1;           // 2x4 wave grid, wave tile 64x64
    int lrow = lane & 15, kg = lane >> 4;

    f32x4 acc[4][4];
    #pragma unroll
    for (int i = 0; i < 4; ++i)
        #pragma unroll
        for (int j = 0; j < 4; ++j) acc[i][j] = (f32x4){0.f, 0.f, 0.f, 0.f};

    int ar = tid >> 2, akg = tid & 3;          // A: row, kgroup (8 floats)
    int agrow = row0 + ar;
    bool avalid = agrow < M;
    int bn_ = tid >> 1, bkh = (tid & 1) * 16;  // B: col, k-half (16 bf16)

    float fa[8];
    bf16x8 bv0, bv1;

    auto loadTile = [&](int k0) {
        if (avalid) {
            const f32x4* p = (const f32x4*)&A[(size_t)agrow * K + k0 + akg * 8];
            *(f32x4*)&fa[0] = p[0];
            *(f32x4*)&fa[4] = p[1];
        }
        const bf16x8* p = (const bf16x8*)&BT[(size_t)bn_ * K + k0 + bkh];
        bv0 = p[0]; bv1 = p[1];
    };
    auto stageTile = [&](int buf) {
        unsigned short av[8];
        #pragma unroll
        for (int q = 0; q < 8; ++q) av[q] = avalid ? f2bf(fa[q]) : (unsigned short)0;
        *(bf16x8*)&Asl[buf][akg][ar][0] = *(bf16x8*)&av[0];
        *(bf16x8*)&Bsl[buf][(bkh >> 3) + 0][bn_][0] = bv0;
        *(bf16x8*)&Bsl[buf][(bkh >> 3) + 1][bn_][0] = bv1;
    };

    int nsteps = K / BK;
    loadTile(0);
    stageTile(0);
    __syncthreads();

    int cur = 0;
    for (int step = 0; step < nsteps; ++step) {
        bool more = (step + 1) < nsteps;
        if (more) loadTile((step + 1) * BK);

        bf16x8 af[4], bfr[4];
        #pragma unroll
        for (int i = 0; i < 4; ++i)
            af[i] = *(bf16x8*)&Asl[cur][kg][wm * 64 + i * 16 + lrow][0];
        #pragma unroll
        for (int j = 0; j < 4; ++j)
            bfr[j] = *(bf16x8*)&Bsl[cur][kg][wn * 64 + j * 16 + lrow][0];
        #pragma unroll
        for (int i = 0; i < 4; ++i)
            #pragma unroll
            for (int j = 0; j < 4; ++j)
                acc[i][j] = __builtin_amdgcn_mfma_f32_16x16x32_bf16(af[i], bfr[j], acc[i][j], 0, 0, 0);

        if (more) stageTile(cur ^ 1);
        __syncthreads();
        cur ^= 1;
    }

    // ---- phase 2: h tile (bias+relu, bf16) into SMEM ----
    #pragma unroll
    for (int i = 0; i < 4; ++i) {
        #pragma unroll
        for (int j = 0; j < 4; ++j) {
            int k2 = wn * 64 + j * 16 + lrow;
            float bv = b1[k2];
            int base = ((k2 >> 5) * 4 + ((k2 >> 3) & 3)) * 1024 + (k2 & 7);
            #pragma unroll
            for (int r = 0; r < 4; ++r) {
                int row = wm * 64 + i * 16 + kg * 4 + r;
                float v = fmaxf(acc[i][j][r] + bv, 0.0f);
                SMEM[base + row * 8] = f2bf(v);
            }
        }
    }
    __syncthreads();

    // ---- phase 3: z0 slice ----
    f32x4 acc2[4];
    #pragma unroll
    for (int i = 0; i < 4; ++i) acc2[i] = (f32x4){0.f, 0.f, 0.f, 0.f};
    int col2 = wn * 16 + lrow;
    #pragma unroll
    for (int ch = 0; ch < 8; ++ch) {           // K2 = Nn = 256 -> 8 chunks of 32
        bf16x8 bfr2 = *(const bf16x8*)&W2bT[(size_t)col2 * Nn + ch * 32 + kg * 8];
        bf16x8 af2[4];
        #pragma unroll
        for (int i = 0; i < 4; ++i)
            af2[i] = *(bf16x8*)&SMEM[(ch * 4 + kg) * 1024 + (wm * 64 + i * 16 + lrow) * 8];
        #pragma unroll
        for (int i = 0; i < 4; ++i)
            acc2[i] = __builtin_amdgcn_mfma_f32_16x16x32_bf16(af2[i], bfr2, acc2[i], 0, 0, 0);
    }
    float bv2 = b2[col2];
    #pragma unroll
    for (int i = 0; i < 4; ++i) {
        #pragma unroll
        for (int r = 0; r < 4; ++r) {
            int grow = row0 + wm * 64 + i * 16 + kg * 4 + r;
            if (grow < M)
                z0out[(size_t)grow * Cn + col2] = f2bf(acc2[i][r] + bv2);
        }
    }
}

// per-node: prefix over NPART partition counts -> pofs; true total -> cntT;
// padded total -> cnt8; block-reduced sum of cnt8 -> bsum (merged scan1)
__global__ __launch_bounds__(256) void combine_k(const int* cntp, int* pofs, int* cntT,
                                                 int* cnt8, int* bsum, int N_) {
    __shared__ int sm[256];
    int t = threadIdx.x;
    int i = blockIdx.x * 256 + t;
    int c8 = 0;
    if (i < N_) {
        int s = 0;
        #pragma unroll
        for (int p = 0; p < NPART; ++p) {
            size_t idx = (size_t)p * N_ + i;
            int v = cntp[idx];
            pofs[idx] = s;
            s += v;
        }
        cntT[i] = s;
        c8 = (s + 7) & ~7;
        cnt8[i] = c8;
    }
    sm[t] = c8;
    __syncthreads();
    for (int off = 128; off; off >>= 1) {
        if (t < off) sm[t] += sm[t + off];
        __syncthreads();
    }
    if (t == 0) bsum[blockIdx.x] = sm[0];
}

__global__ __launch_bounds__(1024) void scan2_k(const int* bsum, int* boff, int nb) {
    __shared__ int sm[1024];
    int t = threadIdx.x;
    int v = (t < nb) ? bsum[t] : 0;
    sm[t] = v;
    __syncthreads();
    for (int off = 1; off < 1024; off <<= 1) {
        int x = (t >= off) ? sm[t - off] : 0;
        __syncthreads();
        sm[t] += x;
        __syncthreads();
    }
    if (t < nb) boff[t] = sm[t] - v;   // exclusive
}

// scan3: rowstart + zero the pad entries of cs (positions [cntT, cnt8) per row)
__global__ __launch_bounds__(256) void scan3_k(const int* cnt8, const int* cntT, const int* boff,
                                               int* rowstart, unsigned int* cs, int N_) {
    __shared__ int sm[256];
    int t = threadIdx.x, i = blockIdx.x * 256 + t;
    int v = (i < N_) ? cnt8[i] : 0;
    sm[t] = v;
    __syncthreads();
    for (int off = 1; off < 256; off <<= 1) {
        int x = (t >= off) ? sm[t - off] : 0;
        __syncthreads();
        sm[t] += x;
        __syncthreads();
    }
    if (i < N_) {
        int base = boff[blockIdx.x] + sm[t] - v;
        rowstart[i] = base;
        int st = cntT[i];
        for (int j = st; j < v; ++j) cs[base + j] = 0;   // pads: src=0,w=0
    }
    if (i == N_ - 1) rowstart[N_] = boff[blockIdx.x] + sm[t];
}

// atomic-free CSR fill: pos = rowstart[c] + pofs[part][c] + rank
// csr entry: src:17 | unorm15(w) << 17
__global__ __launch_bounds__(256) void fill_csr_k(const unsigned long long* epack, const int* pofs,
                                                  const int* rowstart, unsigned int* cs,
                                                  int E_, int N_) {
    int e = blockIdx.x * 256 + threadIdx.x;
    if (e >= E_) return;
    unsigned long long v = epack[e];
    unsigned int r   = (unsigned int)(v & 0x1ffffu);
    int          c   = (int)((v >> 17) & 0x1ffffu);
    unsigned int w15 = (unsigned int)((v >> 34) & 0x7fffu);
    int         part = (int)((v >> 49) & 7u);
    int           rk = (int)(v >> 52);
    int pos = rowstart[c] + pofs[(size_t)part * N_ + c] + rk;
    cs[pos] = r | (w15 << 17);
}

// 32-lane group per node: deg = 1 + sum(w over row, pads are 0); dinv = rsqrt
__global__ __launch_bounds__(256) void deg_dinv_k(const unsigned int* __restrict__ cs,
                                                  const int* __restrict__ rowstart,
                                                  float* __restrict__ dinv, int N_) {
    int node = blockIdx.x * 8 + (threadIdx.x >> 5);
    int l = threadIdx.x & 31;
    if (node >= N_) return;
    int s = rowstart[node], e = rowstart[node + 1];
    float sum = 0.0f;
    for (int j = s + l; j < e; j += 32) sum += (float)(cs[j] >> 17) * U15INV;
    #pragma unroll
    for (int off = 16; off; off >>= 1) sum += __shfl_xor(sum, off, 64);
    float d = sum + 1.0f;   // self-loop
    if (l == 0) dinv[node] = (d > 0.0f) ? rsqrtf(fmaxf(d, 1e-12f)) : 0.0f;
}

// ---------------- propagation: 8 lanes per node, 8 nodes per wave ----------------
// MODE 0: middle iteration. MODE 1: FIRST iteration — cs holds raw w; compute
// nm = dinv[src]*w*dinv[dst] on the fly, use it, write back quantized (lane 0).
// MODE 2: LAST iteration — fused log_softmax, fp32 out.
template<int MODE>
__global__ __launch_bounds__(256) void prop8_k(const unsigned short* __restrict__ z,
                                               const unsigned short* __restrict__ z0,
                                               const int* __restrict__ rowstart,
                                               unsigned int* __restrict__ cs,
                                               const float* __restrict__ dinv,
                                               unsigned short* __restrict__ znew,
                                               float* __restrict__ out, int N_) {
    int node = blockIdx.x * 32 + (threadIdx.x >> 3);
    int l = threadIdx.x & 7;
    if (node >= N_) return;
    int s = rowstart[node], e = rowstart[node + 1];   // multiples of 8
    float d = dinv[node];
    size_t ro = (size_t)node * 64 + l * 8;
    u32x4 zs = *(const u32x4*)&z[ro];
    float dd = d * d;
    float a[8];
    a[0] = dd * bflo(zs.x); a[1] = dd * bfhi(zs.x);
    a[2] = dd * bflo(zs.y); a[3] = dd * bfhi(zs.y);
    a[4] = dd * bflo(zs.z); a[5] = dd * bfhi(zs.z);
    a[6] = dd * bflo(zs.w); a[7] = dd * bfhi(zs.w);

    for (int j = s; j < e; j += 8) {
        u32x4 p0 = __builtin_nontemporal_load((const u32x4*)&cs[j]);
        u32x4 p1 = __builtin_nontemporal_load((const u32x4*)&cs[j + 4]);
        unsigned int pe[8] = { p0.x, p0.y, p0.z, p0.w, p1.x, p1.y, p1.z, p1.w };
        u32x4 g[8];
        #pragma unroll
        for (int q = 0; q < 8; ++q)
            g[q] = *(const u32x4*)&z[(size_t)(pe[q] & 0x1ffffu) * 64 + l * 8];
        if (MODE == 1) {
            float dv[8];
            #pragma unroll
            for (int q = 0; q < 8; ++q) dv[q] = dinv[pe[q] & 0x1ffffu];
            unsigned int ow[8];
            #pragma unroll
            for (int q = 0; q < 8; ++q) {
                float wraw = (float)(pe[q] >> 17) * U15INV;
                float nm = dv[q] * wraw * d;
                ow[q] = (pe[q] & 0x1ffffu) | (u15q(nm) << 17);
                a[0] += nm * bflo(g[q].x); a[1] += nm * bfhi(g[q].x);
                a[2] += nm * bflo(g[q].y); a[3] += nm * bfhi(g[q].y);
                a[4] += nm * bflo(g[q].z); a[5] += nm * bfhi(g[q].z);
                a[6] += nm * bflo(g[q].w); a[7] += nm * bfhi(g[q].w);
            }
            if (l == 0) {
                u32x4 o0, o1;
                o0.x = ow[0]; o0.y = ow[1]; o0.z = ow[2]; o0.w = ow[3];
                o1.x = ow[4]; o1.y = ow[5]; o1.z = ow[6]; o1.w = ow[7];
                *(u32x4*)&cs[j] = o0;
                *(u32x4*)&cs[j + 4] = o1;
            }
        } else {
            #pragma unroll
            for (int q = 0; q < 8; ++q) {
                float w = (float)(pe[q] >> 17) * U15INV;
                a[0] += w * bflo(g[q].x); a[1] += w * bfhi(g[q].x);
                a[2] += w * bflo(g[q].y); a[3] += w * bfhi(g[q].y);
                a[4] += w * bflo(g[q].z); a[5] += w * bfhi(g[q].z);
                a[6] += w * bflo(g[q].w); a[7] += w * bfhi(g[q].w);
            }
        }
    }

    u32x4 z0v = __builtin_nontemporal_load((const u32x4*)&z0[ro]);
    float v[8];
    float z0f[8] = { bflo(z0v.x), bfhi(z0v.x), bflo(z0v.y), bfhi(z0v.y),
                     bflo(z0v.z), bfhi(z0v.z), bflo(z0v.w), bfhi(z0v.w) };
    #pragma unroll
    for (int q = 0; q < 8; ++q) v[q] = (1.0f - ALPHA) * a[q] + ALPHA * z0f[q];

    if (MODE != 2) {
        u32x4 o;
        o.x = pack2(v[0], v[1]); o.y = pack2(v[2], v[3]);
        o.z = pack2(v[4], v[5]); o.w = pack2(v[6], v[7]);
        *(u32x4*)&znew[ro] = o;      // normal store: let z dwell in L2
    } else {
        float m = v[0];
        #pragma unroll
        for (int q = 1; q < 8; ++q) m = fmaxf(m, v[q]);
        #pragma unroll
        for (int off = 1; off < 8; off <<= 1) m = fmaxf(m, __shfl_xor(m, off, 64));
        float sum = 0.0f;
        #pragma unroll
        for (int q = 0; q < 8; ++q) sum += expf(v[q] - m);
        #pragma unroll
        for (int off = 1; off < 8; off <<= 1) sum += __shfl_xor(sum, off, 64);
        float lg = logf(sum);
        float4 o0 = make_float4(v[0] - m - lg, v[1] - m - lg, v[2] - m - lg, v[3] - m - lg);
        float4 o1 = make_float4(v[4] - m - lg, v[5] - m - lg, v[6] - m - lg, v[7] - m - lg);
        *(float4*)&out[ro] = o0;
        *(float4*)&out[ro + 4] = o1;
    }
}

// ---------------- launcher ----------------

extern "C" void kernel_launch(void* const* d_in, const int* in_sizes, int n_in,
                              void* d_out, int out_size, void* d_ws, size_t ws_size,
                              hipStream_t stream) {
    const float* x   = (const float*)d_in[0];
    const void*  ei  = d_in[1];
    const float* ew  = (const float*)d_in[2];
    const float* xw  = (const float*)d_in[3];
    const float* W1  = (const float*)d_in[4];
    const float* b1  = (const float*)d_in[5];
    const float* W2  = (const float*)d_in[6];
    const float* b2  = (const float*)d_in[7];

    const int F_ = in_sizes[3];          // 512
    const int N_ = in_sizes[0] / F_;     // 100000
    const int E_ = in_sizes[2];          // 3200000
    const int D_ = in_sizes[5];          // 256
    const int C_ = in_sizes[7];          // 64

    const int E8 = E_ + 7 * N_;          // upper bound on padded edge count

    char* base = (char*)d_ws;
    size_t off = 0;
    auto take = [&](size_t bytes) -> void* {
        void* p = base + off;
        off += (bytes + 255) & ~(size_t)255;
        return p;
    };
    unsigned long long* epack = (unsigned long long*)take((size_t)E_ * 8);
    unsigned int* cs = (unsigned int*)take((size_t)E8 * 4);
    int*   cntp     = (int*)  take((size_t)NPART * N_ * 4);
    int*   pofs     = (int*)  take((size_t)NPART * N_ * 4);
    int*   cntT     = (int*)  take((size_t)N_ * 4);
    int*   cnt8     = (int*)  take((size_t)N_ * 4);
    float* dinv     = (float*)take((size_t)N_ * 4);
    int*   rowstart = (int*)  take((size_t)(N_ + 1) * 4);
    int*   flag     = (int*)  take(256);
    int*   bsum     = (int*)  take(4096 * 4);
    int*   boff     = (int*)  take(4096 * 4);
    unsigned short* W1bT = (unsigned short*)take((size_t)F_ * D_ * 2);
    unsigned short* W2bT = (unsigned short*)take((size_t)D_ * C_ * 2);
    unsigned short* z0b  = (unsigned short*)take((size_t)N_ * C_ * 2);
    unsigned short* za   = (unsigned short*)take((size_t)N_ * C_ * 2);
    unsigned short* zb   = (unsigned short*)take((size_t)N_ * C_ * 2);

    (void)ws_size; (void)n_in; (void)out_size;

    int nblk = (N_ + 255) / 256;
    int eblk = (E_ + 255) / 256;
    int ncnt = NPART * N_;

    setup_k<<<(ncnt + 255) / 256, 256, 0, stream>>>(cntp, flag, ncnt);
    detect_idx_k<<<1, 256, 0, stream>>>(ei, flag, E_, N_);
    wprep_k<<<(F_ * D_ + D_ * C_ + 255) / 256, 256, 0, stream>>>(W1, xw, W1bT, W2, W2bT, F_, D_, C_);

    // MERGED: fused MLP (first gx blocks) + edge prep (remaining blocks)
    int gx = (N_ + 127) / 128;
    int eblk512 = (E_ + 511) / 512;
    mlp_prep_k<<<gx + eblk512, 512, 0, stream>>>(
        x, W1bT, b1, W2bT, b2, z0b, N_, F_, D_, C_, gx,
        ei, ew, epack, cntp, flag, E_, N_);

    combine_k<<<nblk, 256, 0, stream>>>(cntp, pofs, cntT, cnt8, bsum, N_);
    scan2_k<<<1, 1024, 0, stream>>>(bsum, boff, nblk);
    scan3_k<<<nblk, 256, 0, stream>>>(cnt8, cntT, boff, rowstart, cs, N_);
    fill_csr_k<<<eblk, 256, 0, stream>>>(epack, pofs, rowstart, cs, E_, N_);
    int gblk8 = (N_ + 7) / 8;
    deg_dinv_k<<<gblk8, 256, 0, stream>>>(cs, rowstart, dinv, N_);

    int pblk = (N_ + 31) / 32;
    unsigned short* bufs[2] = { za, zb };
    // it 0: norm fused (cs raw w -> normalized in place), reads z0b
    prop8_k<1><<<pblk, 256, 0, stream>>>(z0b, z0b, rowstart, cs, dinv, za, nullptr, N_);
    const unsigned short* cur = za;
    for (int it = 1; it < K_ITERS - 1; ++it) {
        unsigned short* dst = bufs[it & 1];
        prop8_k<0><<<pblk, 256, 0, stream>>>(cur, z0b, rowstart, cs, dinv, dst, nullptr, N_);
        cur = dst;
    }
    prop8_k<2><<<pblk, 256, 0, stream>>>(cur, z0b, rowstart, cs, dinv, nullptr, (float*)d_out, N_);
}